// Round 1
// baseline (411.252 us; speedup 1.0000x reference)
//
#include <hip/hip_runtime.h>
#include <hip/hip_bf16.h>
#include <math.h>

#define BB 4
#define SS 4096
#define HH 2048
#define VOCAB 32000
#define NLC 8192
#define ROWS (BB*SS)

// feat tiling: 32 rows x 512 cols per block, 256 threads (4 waves)
#define FROWS 32
#define FCOLS 512
#define FEAT_BLOCKS ((NLC / FROWS) * (HH / FCOLS))   // 1024

typedef float fvec4 __attribute__((ext_vector_type(4)));   // native vec: OK for nontemporal builtins

__device__ __forceinline__ float gelu_exact(float x) {
    return 0.5f * x * (1.0f + erff(x * 0.70710678118654752f));
}

// Kernel B: fused scatter_win (blocks 0..31) + MLP chain -> g2 [NLC x 64]
__global__ void mlp_scatter_kernel(const float* __restrict__ lc, const float* __restrict__ W0,
                                   const float* __restrict__ b0, const float* __restrict__ W1,
                                   const float* __restrict__ b1, const float* __restrict__ W2,
                                   const float* __restrict__ b2, float* __restrict__ g2out,
                                   const int* __restrict__ pos_b, const int* __restrict__ pos_s,
                                   int* __restrict__ win) {
    int t = threadIdx.x;
    // winner = max lc index per position (numpy last-write-wins); device-scope atomic
    if (blockIdx.x < NLC / 256) {
        int i = blockIdx.x * 256 + t;
        int p = pos_b[i] * SS + pos_s[i];
        atomicMax(&win[p], i + 1);
    }

    int w = t >> 6;                // wave id: one row per wave
    int j = t & 63;                // intermediate dim
    int row = blockIdx.x * 4 + w;
    __shared__ float g[4][64];
    float x = lc[row];
    float h = gelu_exact(fmaf(x, W0[j], b0[j]));
    g[w][j] = h;
    __syncthreads();
    float acc = b1[j];
#pragma unroll
    for (int k = 0; k < 64; ++k) acc = fmaf(g[w][k], W1[k * 64 + j], acc);
    acc = gelu_exact(acc);
    __syncthreads();               // WAR on g
    g[w][j] = acc;
    __syncthreads();
    float acc2 = b2[j];
#pragma unroll
    for (int k = 0; k < 64; ++k) acc2 = fmaf(g[w][k], W2[k * 64 + j], acc2);
    g2out[row * 64 + j] = gelu_exact(acc2);
}

// Kernel C: fused feat-matmul-scatter (blocks 0..1023, VALU-bound) +
// embedding gather (blocks 1024.., HBM-bound). Complementary pipes overlap.
__global__ void feat_gather_kernel(const float* __restrict__ g2, const int* __restrict__ win,
                                   const int* __restrict__ pos_b, const int* __restrict__ pos_s,
                                   const float* __restrict__ Wout, const float* __restrict__ bout,
                                   const int* __restrict__ ids, const float* __restrict__ wte,
                                   float* __restrict__ out) {
    __shared__ float g2s[FROWS][64];   // 8 KiB (feat path only)
    __shared__ int   wrow[FROWS];
    int t = threadIdx.x;

    if (blockIdx.x >= FEAT_BLOCKS) {
        // ---- gather path: one output row per block ----
        int row = blockIdx.x - FEAT_BLOCKS;
        if (win[row] > 0) return;          // overwritten by feat path
        int id = ids[row];
        id = id < 0 ? 0 : (id > VOCAB - 1 ? VOCAB - 1 : id);
        const fvec4* src = (const fvec4*)(wte + (size_t)id * HH);
        fvec4* dst = (fvec4*)(out + (size_t)row * HH);
        // out is write-once, never re-read: nontemporal to spare L2/L3 for wte
        fvec4 v0 = src[t];
        fvec4 v1 = src[t + 256];
        __builtin_nontemporal_store(v0, &dst[t]);
        __builtin_nontemporal_store(v1, &dst[t + 256]);
        return;
    }

    // ---- feat path: 32 rows x 512 cols register-blocked matmul + scatter ----
    int rblk = blockIdx.x & 255;
    int cb   = (blockIdx.x >> 8) * FCOLS;
    int base = rblk * FROWS;

    {
        const float4* src = (const float4*)(g2 + base * 64);
        float4* dst = (float4*)&g2s[0][0];
        dst[t] = src[t];
        dst[t + 256] = src[t + 256];
    }
    if (t < FROWS) {
        int i = base + t;
        int p = pos_b[i] * SS + pos_s[i];
        wrow[t] = (win[p] == i + 1) ? p : -1;
    }
    __syncthreads();

    int w = t >> 6, l = t & 63;
    const float* wbase = Wout + cb + l * 4;

    float4 bv0 = *(const float4*)&bout[cb + l * 4];
    float4 bv1 = *(const float4*)&bout[cb + 256 + l * 4];
    float4 acc0[8], acc1[8];
#pragma unroll
    for (int r = 0; r < 8; ++r) { acc0[r] = bv0; acc1[r] = bv1; }

    for (int k0 = 0; k0 < 64; k0 += 4) {
        float4 wv0[4], wv1[4];
#pragma unroll
        for (int kk = 0; kk < 4; ++kk) {
            const float* wp = wbase + (size_t)(k0 + kk) * HH;
            wv0[kk] = *(const float4*)wp;
            wv1[kk] = *(const float4*)(wp + 256);
        }
#pragma unroll
        for (int r = 0; r < 8; ++r) {
            float4 gv = *(const float4*)&g2s[w * 8 + r][k0];  // wave-uniform: LDS broadcast
#pragma unroll
            for (int c = 0; c < 4; ++c) {
                float g0 = (&gv.x)[0], g1 = (&gv.x)[1], g2v = (&gv.x)[2], g3 = (&gv.x)[3];
                (&acc0[r].x)[c] = fmaf(g0, (&wv0[0].x)[c],
                                  fmaf(g1, (&wv0[1].x)[c],
                                  fmaf(g2v, (&wv0[2].x)[c],
                                  fmaf(g3, (&wv0[3].x)[c], (&acc0[r].x)[c]))));
                (&acc1[r].x)[c] = fmaf(g0, (&wv1[0].x)[c],
                                  fmaf(g1, (&wv1[1].x)[c],
                                  fmaf(g2v, (&wv1[2].x)[c],
                                  fmaf(g3, (&wv1[3].x)[c], (&acc1[r].x)[c]))));
            }
        }
    }

#pragma unroll
    for (int r = 0; r < 8; ++r) {
        int p = wrow[w * 8 + r];          // wave-uniform
        if (p < 0) continue;
        float* op = out + (size_t)p * HH + cb + l * 4;
        *(float4*)op = acc0[r];
        *(float4*)(op + 256) = acc1[r];
    }
}

extern "C" void kernel_launch(void* const* d_in, const int* in_sizes, int n_in,
                              void* d_out, int out_size, void* d_ws, size_t ws_size,
                              hipStream_t stream) {
    const int*   ids  = (const int*)d_in[0];
    const float* lc   = (const float*)d_in[1];
    const int*   pb   = (const int*)d_in[2];
    const int*   ps   = (const int*)d_in[3];
    const float* wte  = (const float*)d_in[4];
    const float* W0   = (const float*)d_in[5];
    const float* b0   = (const float*)d_in[6];
    const float* W1   = (const float*)d_in[7];
    const float* b1   = (const float*)d_in[8];
    const float* W2   = (const float*)d_in[9];
    const float* b2   = (const float*)d_in[10];
    const float* Wout = (const float*)d_in[11];
    const float* bout = (const float*)d_in[12];
    float* out = (float*)d_out;

    int*   win = (int*)d_ws;                                   // ROWS ints (64 KiB)
    float* g2  = (float*)((char*)d_ws + ROWS * sizeof(int));   // NLC*64 fp32 (2 MiB)

    (void)hipMemsetAsync(win, 0, ROWS * sizeof(int), stream);
    mlp_scatter_kernel<<<NLC / 4, 256, 0, stream>>>(lc, W0, b0, W1, b1, W2, b2, g2, pb, ps, win);
    feat_gather_kernel<<<FEAT_BLOCKS + ROWS, 256, 0, stream>>>(g2, win, pb, ps, Wout, bout, ids, wte, out);
}

// Round 2
// 405.824 us; speedup vs baseline: 1.0134x; 1.0134x over previous
//
#include <hip/hip_runtime.h>
#include <hip/hip_bf16.h>
#include <math.h>

#define BB 4
#define SS 4096
#define HH 2048
#define VOCAB 32000
#define NLC 8192
#define ROWS (BB*SS)

// feat tiling: 32 rows x 512 cols per block, 256 threads (4 waves)
#define FROWS 32
#define FCOLS 512
#define FEAT_BLOCKS ((NLC / FROWS) * (HH / FCOLS))   // 1024

typedef float fvec4 __attribute__((ext_vector_type(4)));   // native vec: OK for nontemporal builtins

__device__ __forceinline__ float gelu_exact(float x) {
    return 0.5f * x * (1.0f + erff(x * 0.70710678118654752f));
}

// Kernel B: fused scatter_win (blocks 0..31) + MLP chain -> g2 [NLC x 64]
__global__ void mlp_scatter_kernel(const float* __restrict__ lc, const float* __restrict__ W0,
                                   const float* __restrict__ b0, const float* __restrict__ W1,
                                   const float* __restrict__ b1, const float* __restrict__ W2,
                                   const float* __restrict__ b2, float* __restrict__ g2out,
                                   const int* __restrict__ pos_b, const int* __restrict__ pos_s,
                                   int* __restrict__ win) {
    int t = threadIdx.x;
    // winner = max lc index per position (numpy last-write-wins); device-scope atomic
    if (blockIdx.x < NLC / 256) {
        int i = blockIdx.x * 256 + t;
        int p = pos_b[i] * SS + pos_s[i];
        atomicMax(&win[p], i + 1);
    }

    int w = t >> 6;                // wave id: one row per wave
    int j = t & 63;                // intermediate dim
    int row = blockIdx.x * 4 + w;
    __shared__ float g[4][64];
    float x = lc[row];
    float h = gelu_exact(fmaf(x, W0[j], b0[j]));
    g[w][j] = h;
    __syncthreads();
    float acc = b1[j];
#pragma unroll
    for (int k = 0; k < 64; ++k) acc = fmaf(g[w][k], W1[k * 64 + j], acc);
    acc = gelu_exact(acc);
    __syncthreads();               // WAR on g
    g[w][j] = acc;
    __syncthreads();
    float acc2 = b2[j];
#pragma unroll
    for (int k = 0; k < 64; ++k) acc2 = fmaf(g[w][k], W2[k * 64 + j], acc2);
    g2out[row * 64 + j] = gelu_exact(acc2);
}

// Kernel C: fused embedding gather (blocks 0..ROWS-1, HBM-bound, launched FIRST —
// it is the long pole) + feat-matmul-scatter (blocks ROWS.., VALU-bound, fills the
// VALU pipe behind the gather). Complementary pipes overlap.
__global__ void feat_gather_kernel(const float* __restrict__ g2, const int* __restrict__ win,
                                   const int* __restrict__ pos_b, const int* __restrict__ pos_s,
                                   const float* __restrict__ Wout, const float* __restrict__ bout,
                                   const int* __restrict__ ids, const float* __restrict__ wte,
                                   float* __restrict__ out) {
    __shared__ float g2s[FROWS][64];   // 8 KiB (feat path only)
    __shared__ int   wrow[FROWS];
    int t = threadIdx.x;

    if (blockIdx.x < ROWS) {
        // ---- gather path: one output row per block ----
        int row = blockIdx.x;
        if (win[row] > 0) return;          // overwritten by feat path
        int id = ids[row];
        id = id < 0 ? 0 : (id > VOCAB - 1 ? VOCAB - 1 : id);
        const fvec4* src = (const fvec4*)(wte + (size_t)id * HH);
        fvec4* dst = (fvec4*)(out + (size_t)row * HH);
        // wte rows: no reuse within an iteration (L3 is blown by the harness fill
        // anyway) -> nontemporal loads keep L2 clean for Wout/g2/win.
        // out is write-once, never re-read: nontemporal stores.
        fvec4 v0 = __builtin_nontemporal_load(&src[t]);
        fvec4 v1 = __builtin_nontemporal_load(&src[t + 256]);
        __builtin_nontemporal_store(v0, &dst[t]);
        __builtin_nontemporal_store(v1, &dst[t + 256]);
        return;
    }

    // ---- feat path: 32 rows x 512 cols register-blocked matmul + scatter ----
    int fid  = blockIdx.x - ROWS;
    int rblk = fid & 255;
    int cb   = (fid >> 8) * FCOLS;
    int base = rblk * FROWS;

    {
        const float4* src = (const float4*)(g2 + base * 64);
        float4* dst = (float4*)&g2s[0][0];
        dst[t] = src[t];
        dst[t + 256] = src[t + 256];
    }
    if (t < FROWS) {
        int i = base + t;
        int p = pos_b[i] * SS + pos_s[i];
        wrow[t] = (win[p] == i + 1) ? p : -1;
    }
    __syncthreads();

    int w = t >> 6, l = t & 63;
    const float* wbase = Wout + cb + l * 4;

    float4 bv0 = *(const float4*)&bout[cb + l * 4];
    float4 bv1 = *(const float4*)&bout[cb + 256 + l * 4];
    float4 acc0[8], acc1[8];
#pragma unroll
    for (int r = 0; r < 8; ++r) { acc0[r] = bv0; acc1[r] = bv1; }

    for (int k0 = 0; k0 < 64; k0 += 4) {
        float4 wv0[4], wv1[4];
#pragma unroll
        for (int kk = 0; kk < 4; ++kk) {
            const float* wp = wbase + (size_t)(k0 + kk) * HH;
            wv0[kk] = *(const float4*)wp;
            wv1[kk] = *(const float4*)(wp + 256);
        }
#pragma unroll
        for (int r = 0; r < 8; ++r) {
            float4 gv = *(const float4*)&g2s[w * 8 + r][k0];  // wave-uniform: LDS broadcast
#pragma unroll
            for (int c = 0; c < 4; ++c) {
                float g0 = (&gv.x)[0], g1 = (&gv.x)[1], g2v = (&gv.x)[2], g3 = (&gv.x)[3];
                (&acc0[r].x)[c] = fmaf(g0, (&wv0[0].x)[c],
                                  fmaf(g1, (&wv0[1].x)[c],
                                  fmaf(g2v, (&wv0[2].x)[c],
                                  fmaf(g3, (&wv0[3].x)[c], (&acc0[r].x)[c]))));
                (&acc1[r].x)[c] = fmaf(g0, (&wv1[0].x)[c],
                                  fmaf(g1, (&wv1[1].x)[c],
                                  fmaf(g2v, (&wv1[2].x)[c],
                                  fmaf(g3, (&wv1[3].x)[c], (&acc1[r].x)[c]))));
            }
        }
    }

#pragma unroll
    for (int r = 0; r < 8; ++r) {
        int p = wrow[w * 8 + r];          // wave-uniform
        if (p < 0) continue;
        float* op = out + (size_t)p * HH + cb + l * 4;
        *(float4*)op = acc0[r];
        *(float4*)(op + 256) = acc1[r];
    }
}

extern "C" void kernel_launch(void* const* d_in, const int* in_sizes, int n_in,
                              void* d_out, int out_size, void* d_ws, size_t ws_size,
                              hipStream_t stream) {
    const int*   ids  = (const int*)d_in[0];
    const float* lc   = (const float*)d_in[1];
    const int*   pb   = (const int*)d_in[2];
    const int*   ps   = (const int*)d_in[3];
    const float* wte  = (const float*)d_in[4];
    const float* W0   = (const float*)d_in[5];
    const float* b0   = (const float*)d_in[6];
    const float* W1   = (const float*)d_in[7];
    const float* b1   = (const float*)d_in[8];
    const float* W2   = (const float*)d_in[9];
    const float* b2   = (const float*)d_in[10];
    const float* Wout = (const float*)d_in[11];
    const float* bout = (const float*)d_in[12];
    float* out = (float*)d_out;

    int*   win = (int*)d_ws;                                   // ROWS ints (64 KiB)
    float* g2  = (float*)((char*)d_ws + ROWS * sizeof(int));   // NLC*64 fp32 (2 MiB)

    (void)hipMemsetAsync(win, 0, ROWS * sizeof(int), stream);
    mlp_scatter_kernel<<<NLC / 4, 256, 0, stream>>>(lc, W0, b0, W1, b1, W2, b2, g2, pb, ps, win);
    feat_gather_kernel<<<ROWS + FEAT_BLOCKS, 256, 0, stream>>>(g2, win, pb, ps, Wout, bout, ids, wte, out);
}